// Round 11
// baseline (205.689 us; speedup 1.0000x reference)
//
#include <hip/hip_runtime.h>

typedef unsigned short u16;
typedef unsigned int u32;
typedef __attribute__((ext_vector_type(8))) short short8;   // 8 bf16 (4 VGPRs)
typedef __attribute__((ext_vector_type(4))) float f32x4;

// ws layout (bytes), all 16B-aligned
#define WS_W3T  0        // float[96]  (W3 augmented: [90]=b3, [91..95]=0)
#define WS_W0F  384      // u16[6][6*64*8]  per-o L1 fragments w/ bias rows k=5..9
#define WS_W1F  37248    // u16[18*64*8]
#define WS_W2F  55680    // u16[18*64*8]
#define WS_CNT  74112    // u32 work counter (prep sets to 2048 every launch)

__device__ __forceinline__ u16 f2b(float f) {  // RNE f32 -> bf16 (prep only)
  union { float f; u32 i; } v; v.f = f;
  u32 i = v.i;
  return (u16)((i + 0x7FFFu + ((i >> 16) & 1u)) >> 16);
}

// 3-op bf16 pair pack (round-half-up + v_perm). Verified R7: -18k VALU cyc/SIMD.
__device__ __forceinline__ u32 pk2(float a, float b) {  // a -> low half, b -> high
  u32 ia = __float_as_uint(a) + 0x8000u;
  u32 ib = __float_as_uint(b) + 0x8000u;
  return __builtin_amdgcn_perm(ib, ia, 0x07060302u);
}

// prep: identical math to R8-R10 (verified absmax 7.8e-3) + counter init.
__global__ void prep_kernel(const float* __restrict__ ac, const float* __restrict__ W0,
                            const float* __restrict__ b0, const float* __restrict__ W1,
                            const float* __restrict__ b1, const float* __restrict__ W2,
                            const float* __restrict__ b2, const float* __restrict__ W3,
                            const float* __restrict__ b3,
                            float* __restrict__ w3t, u16* __restrict__ W0f,
                            u16* __restrict__ W1f, u16* __restrict__ W2f,
                            u32* __restrict__ cnt) {
  int tid = blockIdx.x * blockDim.x + threadIdx.x;
  int nth = gridDim.x * blockDim.x;
  if (tid == 0) *cnt = 2048u;  // tiles 0..2047 are statically assigned
  for (int i = tid; i < 96; i += nth)
    w3t[i] = (i < 90) ? W3[i] : ((i == 90) ? b3[0] : 0.0f);
  // W0f[o][t][lane][jj]: A[m=unit][k]; k<5: taps (W0 rows {5,0,1,2,3});
  // k=5+dd: bias row for device dd of channel o; (k=5+dd, u=90) = 1.0.
  for (int i = tid; i < 6 * 6 * 64 * 8; i += nth) {
    int o = i / 3072, rem = i % 3072;
    int t = rem >> 9, lane = (rem >> 3) & 63, jj = rem & 7;
    int q = lane >> 4, m = lane & 15;
    int k = q * 8 + jj;
    int u = t * 16 + m;
    u16 v = 0;
    if (k < 5) {
      const int rowmap[5] = {5, 0, 1, 2, 3};
      if (u < 90) v = f2b(W0[rowmap[k] * 90 + u]);
    } else if (k < 10) {
      int dd = k - 5;
      if (u < 90) {
        float c0 = ac[(o * 5 + dd) * 2 + 0], c1 = ac[(o * 5 + dd) * 2 + 1];
        v = f2b(b0[u] + c0 * W0[4 * 90 + u] + c1 * W0[6 * 90 + u]);
      } else if (u == 90) {
        v = (u16)0x3F80;  // the "1" unit
      }
    }
    W0f[i] = v;
  }
  // W1f/W2f: A-operands with PERMUTED K so D-layout feeds B directly.
  for (int i = tid; i < 2 * 18 * 64 * 8; i += nth) {
    int which = i / (18 * 64 * 8);
    int j2 = i % (18 * 64 * 8);
    int jj = j2 & 7, lane = (j2 >> 3) & 63, f = j2 >> 9;
    int t = f / 3, ki = f % 3;
    int qA = lane >> 4, m = lane & 15;
    int row = 32 * ki + 16 * (jj >> 2) + 4 * qA + (jj & 3);
    int col = 16 * t + m;
    const float* W = which ? W2 : W1;
    const float* bb = which ? b2 : b1;
    u16 v = 0;
    if (row < 90 && col < 90) v = f2b(W[row * 90 + col]);
    else if (row == 90) v = (col < 90) ? f2b(bb[col]) : ((col == 90) ? (u16)0x3F80 : (u16)0);
    (which ? W2f : W1f)[j2] = v;
  }
}

__device__ __forceinline__ f32x4 mfma16(short8 a, short8 b, f32x4 c) {
  return __builtin_amdgcn_mfma_f32_16x16x32_bf16(a, b, c, 0, 0, 0);
}

__device__ __forceinline__ short8 packB(const f32x4& a0, const f32x4& a1) {
  union { u32 u[4]; short8 s; } fu;
  fu.u[0] = pk2(fmaxf(a0.x, 0.f), fmaxf(a0.y, 0.f));
  fu.u[1] = pk2(fmaxf(a0.z, 0.f), fmaxf(a0.w, 0.f));
  fu.u[2] = pk2(fmaxf(a1.x, 0.f), fmaxf(a1.y, 0.f));
  fu.u[3] = pk2(fmaxf(a1.z, 0.f), fmaxf(a1.w, 0.f));
  return fu.s;
}

// R11: persistent waves + dynamic work-stealing. 512 blocks = 2048 waves;
// wave's first tile = its global id, further tiles pulled via device-scope
// atomicAdd (counter in ws, re-initialized by prep each launch — graph-safe).
// Kills R8-R10's ~10% dispatch-tail (1350 blocks / 256 CUs = 5.27 rounds,
// coarse 2-tile granularity). Weights stay register-resident across grabs;
// only the o-dependent w0f (6 L2-hit dwordx4) reloads per tile. Inner loop
// = R8's (best measured: 54.9 us); R9/R10 proved it insensitive to
// occupancy/ILP restructuring, so only the schedule changes this round.
__global__ __launch_bounds__(256, 2) void mlp_kernel(
    const float* __restrict__ x, const float* __restrict__ w3t,
    const u16* __restrict__ W0f, const u16* __restrict__ W1f,
    const u16* __restrict__ W2f, u32* __restrict__ cnt,
    float* __restrict__ out) {
  const int lane = threadIdx.x & 63;
  const int wv = threadIdx.x >> 6;
  const int q = lane >> 4, n = lane & 15;
  const int wid = blockIdx.x * 4 + wv;  // 0..2047

  // o-independent resident weights: w1f (72) + w2f (72) + w3v (4)
  short8 w1f[6][3], w2f[6][3];
  const short8* p1 = (const short8*)W1f;
  const short8* p2 = (const short8*)W2f;
#pragma unroll
  for (int t = 0; t < 6; ++t)
#pragma unroll
    for (int ki = 0; ki < 3; ++ki) {
      w1f[t][ki] = p1[(t * 3 + ki) * 64 + lane];
      w2f[t][ki] = p2[(t * 3 + ki) * 64 + lane];
    }
  f32x4 w3v[6];
#pragma unroll
  for (int t = 0; t < 6; ++t) w3v[t] = *(const f32x4*)(w3t + t * 16 + q * 4);

  const f32x4 z4 = {0.f, 0.f, 0.f, 0.f};

  int tile = wid;
#pragma unroll 1
  while (tile < 10800) {
    const int seg = tile / 225;            // b*6+o
    const int l0 = (tile % 225) * 16;
    const int bb = seg / 6, o = seg % 6;

    // reload the o-dependent L1 fragments (6 x dwordx4, L2-hit)
    short8 w0f[6];
    const short8* p0 = (const short8*)W0f + o * 384;
#pragma unroll
    for (int t = 0; t < 6; ++t) w0f[t] = p0[t * 64 + lane];

    const int l = l0 + n;
    const int oh = l / 60, ow = l - oh * 60;
    const float* xrow = x + (bb * 4096 + oh * 64 + ow);

    float outAcc = 0.f;
    // prefetch taps for d=0
    float pa0 = xrow[0], pa1 = xrow[1], pa2 = xrow[2], pa3 = xrow[3], pa4 = xrow[4];

#pragma unroll 1
    for (int d = 0; d < 5; ++d) {
      float c0 = pa0, c1 = pa1, c2 = pa2, c3 = pa3, c4 = pa4;
      if (d < 4) {  // issue next d's tap loads now
        const float* xp = xrow + (d + 1) * 64;
        pa0 = xp[0]; pa1 = xp[1]; pa2 = xp[2]; pa3 = xp[3]; pa4 = xp[4];
      }

      // one-hot(d) bias-selector slots k=5..9 (wave-uniform -> SALU)
      const u32 u3c = (d == 1) ? 0x00003F80u : ((d == 2) ? 0x3F800000u : 0u);  // k6,k7
      const u32 q1c = (d == 3) ? 0x00003F80u : ((d == 4) ? 0x3F800000u : 0u);  // k8,k9
      const float k5f = (d == 0) ? 1.0f : 0.0f;                                // k5

      union { u32 u[4]; short8 s; } bu;
      u32 t01 = pk2(c0, c1);
      bu.u[0] = (q == 1) ? q1c : t01;  // q0: taps k0,k1; q1: one-hot k8,k9
      bu.u[1] = pk2(c2, c3);           // q0: k2,k3 (other quads hit zero rows)
      bu.u[2] = pk2(c4, k5f);          // q0: k4 + one-hot k5
      bu.u[3] = u3c;                   // q0: k6,k7
      short8 bx = bu.s;

      // ---- L1 (C = 0; bias rides W0f rows 5..9 via the one-hot)
      f32x4 acc[6];
#pragma unroll
      for (int t = 0; t < 6; ++t) acc[t] = mfma16(w0f[t], bx, z4);

      short8 h[3];
#pragma unroll
      for (int ki = 0; ki < 3; ++ki) h[ki] = packB(acc[2 * ki], acc[2 * ki + 1]);

      // ---- L2 (resident w1f)
#pragma unroll
      for (int t = 0; t < 6; ++t) {
        f32x4 a = z4;
#pragma unroll
        for (int ki = 0; ki < 3; ++ki) a = mfma16(w1f[t][ki], h[ki], a);
        acc[t] = a;
      }
#pragma unroll
      for (int ki = 0; ki < 3; ++ki) h[ki] = packB(acc[2 * ki], acc[2 * ki + 1]);

      // ---- L3 (resident w2f) + L4 dot with augmented W3
#pragma unroll
      for (int t = 0; t < 6; ++t) {
        f32x4 a = z4;
#pragma unroll
        for (int ki = 0; ki < 3; ++ki) a = mfma16(w2f[t][ki], h[ki], a);
        outAcc += fmaxf(a.x, 0.f) * w3v[t].x + fmaxf(a.y, 0.f) * w3v[t].y +
                  fmaxf(a.z, 0.f) * w3v[t].z + fmaxf(a.w, 0.f) * w3v[t].w;
      }
    }  // d

    // reduce quad-partials and store
    outAcc += __shfl_xor(outAcc, 16, 64);
    outAcc += __shfl_xor(outAcc, 32, 64);
    if (lane < 16) out[seg * 3600 + l0 + lane] = outAcc;

    // grab next tile (one device-scope atomic per wave)
    u32 nt = 0;
    if (lane == 0) nt = atomicAdd(cnt, 1u);
    tile = __shfl((int)nt, 0, 64);
  }
}

extern "C" void kernel_launch(void* const* d_in, const int* in_sizes, int n_in,
                              void* d_out, int out_size, void* d_ws, size_t ws_size,
                              hipStream_t stream) {
  const float* x  = (const float*)d_in[0];
  const float* ac = (const float*)d_in[1];
  const float* W0 = (const float*)d_in[2];
  const float* b0 = (const float*)d_in[3];
  const float* W1 = (const float*)d_in[4];
  const float* b1 = (const float*)d_in[5];
  const float* W2 = (const float*)d_in[6];
  const float* b2 = (const float*)d_in[7];
  const float* W3 = (const float*)d_in[8];
  const float* b3 = (const float*)d_in[9];
  float* out = (float*)d_out;
  char* ws = (char*)d_ws;
  float* w3t = (float*)(ws + WS_W3T);
  u16* W0f = (u16*)(ws + WS_W0F);
  u16* W1f = (u16*)(ws + WS_W1F);
  u16* W2f = (u16*)(ws + WS_W2F);
  u32* cnt = (u32*)(ws + WS_CNT);
  prep_kernel<<<128, 256, 0, stream>>>(ac, W0, b0, W1, b1, W2, b2, W3, b3,
                                       w3t, W0f, W1f, W2f, cnt);
  mlp_kernel<<<512, 256, 0, stream>>>(x, w3t, W0f, W1f, W2f, cnt, out);
}

// Round 12
// 117.462 us; speedup vs baseline: 1.7511x; 1.7511x over previous
//
#include <hip/hip_runtime.h>

typedef unsigned short u16;
typedef unsigned int u32;
typedef __attribute__((ext_vector_type(8))) short short8;   // 8 bf16 (4 VGPRs)
typedef __attribute__((ext_vector_type(4))) float f32x4;

// ws layout (bytes), all 16B-aligned
#define WS_W3T  0        // float[96]  (W3 augmented: [90]=b3, [91..95]=0)
#define WS_W0F  384      // u16[6][6*64*8]  per-o L1 fragments w/ bias rows k=5..9
#define WS_W1F  37248    // u16[18*64*8]
#define WS_W2F  55680    // u16[18*64*8]   (ends 74112)

__device__ __forceinline__ u16 f2b(float f) {  // RNE f32 -> bf16 (prep only)
  union { float f; u32 i; } v; v.f = f;
  u32 i = v.i;
  return (u16)((i + 0x7FFFu + ((i >> 16) & 1u)) >> 16);
}

// 3-op bf16 pair pack (round-half-up + v_perm). Verified R7: -18k VALU cyc/SIMD.
__device__ __forceinline__ u32 pk2(float a, float b) {  // a -> low half, b -> high
  u32 ia = __float_as_uint(a) + 0x8000u;
  u32 ib = __float_as_uint(b) + 0x8000u;
  return __builtin_amdgcn_perm(ib, ia, 0x07060302u);
}

// Compiler-only memory barrier: pins ds_reads into their chunks (prevents
// the full-unroll hoist of 18 fragment reads = 72 transient VGPRs).
__device__ __forceinline__ void lds_compiler_fence() {
  asm volatile("" ::: "memory");
}

// prep: identical math to R8 (verified absmax 7.8e-3).
__global__ void prep_kernel(const float* __restrict__ ac, const float* __restrict__ W0,
                            const float* __restrict__ b0, const float* __restrict__ W1,
                            const float* __restrict__ b1, const float* __restrict__ W2,
                            const float* __restrict__ b2, const float* __restrict__ W3,
                            const float* __restrict__ b3,
                            float* __restrict__ w3t, u16* __restrict__ W0f,
                            u16* __restrict__ W1f, u16* __restrict__ W2f) {
  int tid = blockIdx.x * blockDim.x + threadIdx.x;
  int nth = gridDim.x * blockDim.x;
  for (int i = tid; i < 96; i += nth)
    w3t[i] = (i < 90) ? W3[i] : ((i == 90) ? b3[0] : 0.0f);
  // W0f[o][t][lane][jj]: A[m=unit][k]; k<5: taps (W0 rows {5,0,1,2,3});
  // k=5+dd: bias row for device dd of channel o; (k=5+dd, u=90) = 1.0.
  for (int i = tid; i < 6 * 6 * 64 * 8; i += nth) {
    int o = i / 3072, rem = i % 3072;
    int t = rem >> 9, lane = (rem >> 3) & 63, jj = rem & 7;
    int q = lane >> 4, m = lane & 15;
    int k = q * 8 + jj;
    int u = t * 16 + m;
    u16 v = 0;
    if (k < 5) {
      const int rowmap[5] = {5, 0, 1, 2, 3};
      if (u < 90) v = f2b(W0[rowmap[k] * 90 + u]);
    } else if (k < 10) {
      int dd = k - 5;
      if (u < 90) {
        float c0 = ac[(o * 5 + dd) * 2 + 0], c1 = ac[(o * 5 + dd) * 2 + 1];
        v = f2b(b0[u] + c0 * W0[4 * 90 + u] + c1 * W0[6 * 90 + u]);
      } else if (u == 90) {
        v = (u16)0x3F80;  // the "1" unit
      }
    }
    W0f[i] = v;
  }
  // W1f/W2f: A-operands with PERMUTED K so D-layout feeds B directly.
  for (int i = tid; i < 2 * 18 * 64 * 8; i += nth) {
    int which = i / (18 * 64 * 8);
    int j2 = i % (18 * 64 * 8);
    int jj = j2 & 7, lane = (j2 >> 3) & 63, f = j2 >> 9;
    int t = f / 3, ki = f % 3;
    int qA = lane >> 4, m = lane & 15;
    int row = 32 * ki + 16 * (jj >> 2) + 4 * qA + (jj & 3);
    int col = 16 * t + m;
    const float* W = which ? W2 : W1;
    const float* bb = which ? b2 : b1;
    u16 v = 0;
    if (row < 90 && col < 90) v = f2b(W[row * 90 + col]);
    else if (row == 90) v = (col < 90) ? f2b(bb[col]) : ((col == 90) ? (u16)0x3F80 : (u16)0);
    (which ? W2f : W1f)[j2] = v;
  }
}

__device__ __forceinline__ f32x4 mfma16(short8 a, short8 b, f32x4 c) {
  return __builtin_amdgcn_mfma_f32_16x16x32_bf16(a, b, c, 0, 0, 0);
}

__device__ __forceinline__ short8 packB(const f32x4& a0, const f32x4& a1) {
  union { u32 u[4]; short8 s; } fu;
  fu.u[0] = pk2(fmaxf(a0.x, 0.f), fmaxf(a0.y, 0.f));
  fu.u[1] = pk2(fmaxf(a0.z, 0.f), fmaxf(a0.w, 0.f));
  fu.u[2] = pk2(fmaxf(a1.x, 0.f), fmaxf(a1.y, 0.f));
  fu.u[3] = pk2(fmaxf(a1.z, 0.f), fmaxf(a1.w, 0.f));
  return fu.s;
}

// R12: same math as R8, different residency. W1/W2/W3 stream from a single
// block-shared LDS copy (37.2 KB -> 4 blocks/CU); only the o-fixed w0f is
// register-resident (blocks specialize on o = blockIdx%6). Chunk-of-2-t
// structure consumes each acc pair immediately -> no acc[] array, peak
// ~110 arch VGPRs -> TRUE 4 waves/SIMD under (256,4). R8-R11 evidence:
// wall is dependency-stall-bound (~40% idle, neither pipe saturated) at a
// register-forced 2 waves/SIMD; this buys the waves that hide the stalls.
__global__ __launch_bounds__(256, 4) void mlp_kernel(
    const float* __restrict__ x, const float* __restrict__ w3t,
    const u16* __restrict__ W0f, const u16* __restrict__ W1f,
    const u16* __restrict__ W2f, float* __restrict__ out) {
  __shared__ short8 ldsW1[18 * 64];  // 18432 B
  __shared__ short8 ldsW2[18 * 64];  // 18432 B
  __shared__ float ldsW3[96];        // 384 B  => 37248 B total, 4 blocks/CU
  const int tid = threadIdx.x;
  const int o = blockIdx.x % 6;    // block's output channel
  const int bi = blockIdx.x / 6;   // 0..224
  {  // cooperative one-time fill
    const uint4* s1 = (const uint4*)W1f;
    const uint4* s2 = (const uint4*)W2f;
    uint4* d1 = (uint4*)ldsW1;
    uint4* d2 = (uint4*)ldsW2;
#pragma unroll
    for (int i = 0; i < 5; ++i) {
      int j = tid + i * 256;
      if (j < 1152) { d1[j] = s1[j]; d2[j] = s2[j]; }
    }
    if (tid < 96) ldsW3[tid] = w3t[tid];
  }
  __syncthreads();  // only barrier; LDS is read-only afterwards

  const int lane = tid & 63;
  const int wv = tid >> 6;
  const int q = lane >> 4, n = lane & 15;

  // resident o-specific L1 fragments (24 VGPRs)
  short8 w0f[6];
  const short8* p0 = (const short8*)W0f + o * 384;
#pragma unroll
  for (int t = 0; t < 6; ++t) w0f[t] = p0[t * 64 + lane];

  const f32x4 z4 = {0.f, 0.f, 0.f, 0.f};

#pragma unroll 1
  for (int e = 0; e < 2; ++e) {
    const int f = bi * 8 + wv * 2 + e;   // 0..1799 within this o
    const int bb = f / 225, idx = f % 225;
    const int seg = bb * 6 + o;
    const int l0 = idx * 16;
    const int l = l0 + n;
    const int oh = l / 60, ow = l - oh * 60;
    const float* xrow = x + (bb * 4096 + oh * 64 + ow);

    float outAcc = 0.f;
    float pa0 = xrow[0], pa1 = xrow[1], pa2 = xrow[2], pa3 = xrow[3], pa4 = xrow[4];

#pragma unroll 1
    for (int d = 0; d < 5; ++d) {
      float c0 = pa0, c1 = pa1, c2 = pa2, c3 = pa3, c4 = pa4;
      if (d < 4) {
        const float* xp = xrow + (d + 1) * 64;
        pa0 = xp[0]; pa1 = xp[1]; pa2 = xp[2]; pa3 = xp[3]; pa4 = xp[4];
      }

      // one-hot(d) bias-selector slots k=5..9 (wave-uniform -> SALU)
      const u32 u3c = (d == 1) ? 0x00003F80u : ((d == 2) ? 0x3F800000u : 0u);  // k6,k7
      const u32 q1c = (d == 3) ? 0x00003F80u : ((d == 4) ? 0x3F800000u : 0u);  // k8,k9
      const float k5f = (d == 0) ? 1.0f : 0.0f;                                // k5

      union { u32 u[4]; short8 s; } bu;
      u32 t01 = pk2(c0, c1);
      bu.u[0] = (q == 1) ? q1c : t01;  // q0: taps k0,k1; q1: one-hot k8,k9
      bu.u[1] = pk2(c2, c3);           // q0: k2,k3 (other quads hit zero rows)
      bu.u[2] = pk2(c4, k5f);          // q0: k4 + one-hot k5
      bu.u[3] = u3c;                   // q0: k6,k7
      short8 bx = bu.s;

      // ---- L1: chunk-of-2-t, pack immediately (no acc array)
      short8 h[3];
#pragma unroll
      for (int c = 0; c < 3; ++c) {
        f32x4 a0 = mfma16(w0f[2 * c + 0], bx, z4);
        f32x4 a1 = mfma16(w0f[2 * c + 1], bx, z4);
        h[c] = packB(a0, a1);
      }

      // ---- L2 streamed from LDS, chunk-of-2-t
      short8 g[3];
#pragma unroll
      for (int c = 0; c < 3; ++c) {
        lds_compiler_fence();
        const short8* pb = &ldsW1[c * 6 * 64 + lane];
        f32x4 a0 = mfma16(pb[0 * 64], h[0], z4);
        a0 = mfma16(pb[1 * 64], h[1], a0);
        a0 = mfma16(pb[2 * 64], h[2], a0);
        f32x4 a1 = mfma16(pb[3 * 64], h[0], z4);
        a1 = mfma16(pb[4 * 64], h[1], a1);
        a1 = mfma16(pb[5 * 64], h[2], a1);
        g[c] = packB(a0, a1);
      }

      // ---- L3 streamed from LDS + L4 dot, chunk-of-2-t
#pragma unroll
      for (int c = 0; c < 3; ++c) {
        lds_compiler_fence();
        const short8* pb = &ldsW2[c * 6 * 64 + lane];
        f32x4 a0 = mfma16(pb[0 * 64], g[0], z4);
        a0 = mfma16(pb[1 * 64], g[1], a0);
        a0 = mfma16(pb[2 * 64], g[2], a0);
        f32x4 a1 = mfma16(pb[3 * 64], g[0], z4);
        a1 = mfma16(pb[4 * 64], g[1], a1);
        a1 = mfma16(pb[5 * 64], g[2], a1);
        f32x4 w3a = *(const f32x4*)&ldsW3[(2 * c + 0) * 16 + q * 4];
        f32x4 w3b = *(const f32x4*)&ldsW3[(2 * c + 1) * 16 + q * 4];
        outAcc += fmaxf(a0.x, 0.f) * w3a.x + fmaxf(a0.y, 0.f) * w3a.y +
                  fmaxf(a0.z, 0.f) * w3a.z + fmaxf(a0.w, 0.f) * w3a.w;
        outAcc += fmaxf(a1.x, 0.f) * w3b.x + fmaxf(a1.y, 0.f) * w3b.y +
                  fmaxf(a1.z, 0.f) * w3b.z + fmaxf(a1.w, 0.f) * w3b.w;
      }
    }  // d

    // reduce quad-partials and store
    outAcc += __shfl_xor(outAcc, 16, 64);
    outAcc += __shfl_xor(outAcc, 32, 64);
    if (lane < 16) out[seg * 3600 + l0 + lane] = outAcc;
  }  // e
}

extern "C" void kernel_launch(void* const* d_in, const int* in_sizes, int n_in,
                              void* d_out, int out_size, void* d_ws, size_t ws_size,
                              hipStream_t stream) {
  const float* x  = (const float*)d_in[0];
  const float* ac = (const float*)d_in[1];
  const float* W0 = (const float*)d_in[2];
  const float* b0 = (const float*)d_in[3];
  const float* W1 = (const float*)d_in[4];
  const float* b1 = (const float*)d_in[5];
  const float* W2 = (const float*)d_in[6];
  const float* b2 = (const float*)d_in[7];
  const float* W3 = (const float*)d_in[8];
  const float* b3 = (const float*)d_in[9];
  float* out = (float*)d_out;
  char* ws = (char*)d_ws;
  float* w3t = (float*)(ws + WS_W3T);
  u16* W0f = (u16*)(ws + WS_W0F);
  u16* W1f = (u16*)(ws + WS_W1F);
  u16* W2f = (u16*)(ws + WS_W2F);
  prep_kernel<<<128, 256, 0, stream>>>(ac, W0, b0, W1, b1, W2, b2, W3, b3,
                                       w3t, W0f, W1f, W2f);
  mlp_kernel<<<1350, 256, 0, stream>>>(x, w3t, W0f, W1f, W2f, out);
}